// Round 2
// baseline (105.339 us; speedup 1.0000x reference)
//
#include <hip/hip_runtime.h>
#include <math.h>

#define NG 1024
#define W_RES 128
#define H_RES 128
#define NPIX (W_RES * H_RES)
#define NCHUNK 8
#define CH (NG / NCHUNK)

// Scratch in device globals: fully rewritten every call (no reliance on prior state),
// avoids any assumption about ws_size. 48KB params + 3MB partials.
__device__ float g_sorted[NG * 12];
__device__ float g_part[6 * NCHUNK * NPIX];

// ---------------------------------------------------------------------------
// Kernel 1: per-gaussian preprocess + bitonic depth-sort (one block, 1024 thr)
// Produces g_sorted[t*12 + {px,py,ia,ib,ic,opac,r,g,b,depth,pad,pad}] in
// ascending-depth order.
// ---------------------------------------------------------------------------
__global__ __launch_bounds__(1024) void prep_sort_kernel(
    const float* __restrict__ means, const float* __restrict__ log_scales,
    const float* __restrict__ quats, const float* __restrict__ opacity_logits,
    const float* __restrict__ colors, const float* __restrict__ cam,
    const float* __restrict__ look, const float* __restrict__ up) {
  __shared__ float sp[NG * 12];   // 48 KB
  __shared__ float skey[NG];
  __shared__ int sval[NG];
  const int t = threadIdx.x;

  // ---- camera basis (redundant per thread; trivially cheap) ----
  const float cpx = cam[0], cpy = cam[1], cpz = cam[2];
  float fx0 = look[0] - cpx, fy0 = look[1] - cpy, fz0 = look[2] - cpz;
  float inv = 1.f / (sqrtf(fx0 * fx0 + fy0 * fy0 + fz0 * fz0) + 1e-8f);
  const float fX = fx0 * inv, fY = fy0 * inv, fZ = fz0 * inv;
  const float ux0 = up[0], uy0 = up[1], uz0 = up[2];
  float rX0 = fY * uz0 - fZ * uy0, rY0 = fZ * ux0 - fX * uz0, rZ0 = fX * uy0 - fY * ux0;
  inv = 1.f / (sqrtf(rX0 * rX0 + rY0 * rY0 + rZ0 * rZ0) + 1e-8f);
  const float rX = rX0 * inv, rY = rY0 * inv, rZ = rZ0 * inv;
  float uX0 = rY * fZ - rZ * fY, uY0 = rZ * fX - rX * fZ, uZ0 = rX * fY - rY * fX;
  inv = 1.f / (sqrtf(uX0 * uX0 + uY0 * uY0 + uZ0 * uZ0) + 1e-8f);
  const float uX = uX0 * inv, uY = uY0 * inv, uZ = uZ0 * inv;
  const float V00 = rX, V01 = rY, V02 = rZ, V03 = -(rX * cpx + rY * cpy + rZ * cpz);
  const float V10 = uX, V11 = uY, V12 = uZ, V13 = -(uX * cpx + uY * cpy + uZ * cpz);
  const float V20 = -fX, V21 = -fY, V22 = -fZ, V23 = (fX * cpx + fY * cpy + fZ * cpz);

  const float foc = 1.7320508075688772f;  // 1/tan(30deg)
  const float fpx = foc * 64.f;           // focal in pixels (aspect=1)
  const float fpy = foc * 64.f;

  // ---- per-gaussian ----
  {
    float qw = quats[4 * t + 0], qx = quats[4 * t + 1], qy = quats[4 * t + 2], qz = quats[4 * t + 3];
    float qinv = 1.f / (sqrtf(qw * qw + qx * qx + qy * qy + qz * qz) + 1e-8f);
    qw *= qinv; qx *= qinv; qy *= qinv; qz *= qinv;
    const float R00 = 1.f - 2.f * (qy * qy + qz * qz), R01 = 2.f * (qx * qy - qw * qz), R02 = 2.f * (qx * qz + qw * qy);
    const float R10 = 2.f * (qx * qy + qw * qz), R11 = 1.f - 2.f * (qx * qx + qz * qz), R12 = 2.f * (qy * qz - qw * qx);
    const float R20 = 2.f * (qx * qz - qw * qy), R21 = 2.f * (qy * qz + qw * qx), R22 = 1.f - 2.f * (qx * qx + qy * qy);
    const float s0 = __expf(log_scales[3 * t + 0]);
    const float s1 = __expf(log_scales[3 * t + 1]);
    const float s2 = __expf(log_scales[3 * t + 2]);
    const float M00 = R00 * s0, M01 = R01 * s1, M02 = R02 * s2;
    const float M10 = R10 * s0, M11 = R11 * s1, M12 = R12 * s2;
    const float M20 = R20 * s0, M21 = R21 * s1, M22 = R22 * s2;
    const float c00 = M00 * M00 + M01 * M01 + M02 * M02;
    const float c01 = M00 * M10 + M01 * M11 + M02 * M12;
    const float c02 = M00 * M20 + M01 * M21 + M02 * M22;
    const float c11 = M10 * M10 + M11 * M11 + M12 * M12;
    const float c12 = M10 * M20 + M11 * M21 + M12 * M22;
    const float c22 = M20 * M20 + M21 * M21 + M22 * M22;
    const float mx = means[3 * t + 0], my = means[3 * t + 1], mz = means[3 * t + 2];
    const float tx = V00 * mx + V01 * my + V02 * mz + V03;
    const float ty = V10 * mx + V11 * my + V12 * mz + V13;
    const float tz = V20 * mx + V21 * my + V22 * mz + V23;
    const float depth = -tz;
    const float cw = (fabsf(depth) < 1e-6f) ? 1e-6f : depth;  // clip.w == depth
    const float pxs = (foc * tx / cw + 1.f) * 0.5f * (float)W_RES;
    const float pys = (foc * ty / cw + 1.f) * 0.5f * (float)H_RES;
    const float zs = (fabsf(tz) < 1e-6f) ? 1e-6f : tz;
    const float J00 = fpx / zs, J02 = -fpx * tx / (zs * zs);
    const float J11 = fpy / zs, J12 = -fpy * ty / (zs * zs);
    const float T00 = J00 * V00 + J02 * V20;
    const float T01 = J00 * V01 + J02 * V21;
    const float T02 = J00 * V02 + J02 * V22;
    const float T10 = J11 * V10 + J12 * V20;
    const float T11 = J11 * V11 + J12 * V21;
    const float T12 = J11 * V12 + J12 * V22;
    const float t00 = T00 * c00 + T01 * c01 + T02 * c02;
    const float t01 = T00 * c01 + T01 * c11 + T02 * c12;
    const float t02 = T00 * c02 + T01 * c12 + T02 * c22;
    const float t10 = T10 * c00 + T11 * c01 + T12 * c02;
    const float t11 = T10 * c01 + T11 * c11 + T12 * c12;
    const float t12 = T10 * c02 + T11 * c12 + T12 * c22;
    const float a = t00 * T00 + t01 * T01 + t02 * T02 + 0.3f;
    const float bb = t00 * T10 + t01 * T11 + t02 * T12;
    const float c = t10 * T10 + t11 * T11 + t12 * T12 + 0.3f;
    const float det = fmaxf(a * c - bb * bb, 1e-6f);
    const float ia = c / det, ib = -bb / det, ic = a / det;
    float op = 1.f / (1.f + __expf(-opacity_logits[t]));
    const bool valid = (depth > 0.1f) && (depth < 100.f);
    if (!valid) op = 0.f;
    const float cr = 1.f / (1.f + __expf(-colors[3 * t + 0]));
    const float cg = 1.f / (1.f + __expf(-colors[3 * t + 1]));
    const float cb = 1.f / (1.f + __expf(-colors[3 * t + 2]));
    float* s = sp + t * 12;
    s[0] = pxs; s[1] = pys; s[2] = ia; s[3] = ib; s[4] = ic; s[5] = op;
    s[6] = cr;  s[7] = cg;  s[8] = cb; s[9] = depth; s[10] = 0.f; s[11] = 0.f;
    skey[t] = depth;
    sval[t] = t;
  }
  __syncthreads();

  // ---- bitonic sort ascending by depth (keys distinct w.p. 1) ----
  for (int k = 2; k <= NG; k <<= 1) {
    for (int j = k >> 1; j > 0; j >>= 1) {
      const int ixj = t ^ j;
      if (ixj > t) {
        const float ka = skey[t], kb = skey[ixj];
        const bool asc = ((t & k) == 0);
        if (asc ? (ka > kb) : (ka < kb)) {
          skey[t] = kb; skey[ixj] = ka;
          const int va = sval[t]; sval[t] = sval[ixj]; sval[ixj] = va;
        }
      }
      __syncthreads();
    }
  }

  // ---- gather into sorted order, write to global ----
  {
    const int src = sval[t];
    const float* s = sp + src * 12;
    float* d = g_sorted + t * 12;
#pragma unroll
    for (int k2 = 0; k2 < 12; ++k2) d[k2] = s[k2];
  }
}

// ---------------------------------------------------------------------------
// Kernel 2: chunked front-to-back compositing. grid = (NPIX/256, NCHUNK).
// Each thread owns one pixel; gaussian reads are wave-uniform (scalar loads).
// Emits per-chunk partial sums + transmittance (associative combine later).
// ---------------------------------------------------------------------------
__global__ __launch_bounds__(256) void render_chunk_kernel() {
  const int p = blockIdx.x * 256 + threadIdx.x;
  const int chunk = blockIdx.y;
  const float u = (float)(p & (W_RES - 1)) + 0.5f;
  const float v = (float)(p >> 7) + 0.5f;
  const float* __restrict__ g = g_sorted + chunk * CH * 12;
  float T = 1.f, ar = 0.f, ag = 0.f, ab = 0.f, ad = 0.f, aa = 0.f;
#pragma unroll 4
  for (int n = 0; n < CH; ++n) {
    const float gpx = g[n * 12 + 0], gpy = g[n * 12 + 1];
    const float ia = g[n * 12 + 2], ib = g[n * 12 + 3], ic = g[n * 12 + 4];
    const float op = g[n * 12 + 5];
    const float cr = g[n * 12 + 6], cg = g[n * 12 + 7], cb = g[n * 12 + 8];
    const float dep = g[n * 12 + 9];
    const float dx = gpx - u, dy = gpy - v;
    float pw = -0.5f * (ia * dx * dx + 2.f * ib * dx * dy + ic * dy * dy);
    pw = fminf(pw, 0.f);
    const float w = fminf(op * __expf(pw), 0.99f);
    const float ctr = T * w;
    ar += ctr * cr; ag += ctr * cg; ab += ctr * cb;
    ad += ctr * dep; aa += ctr;
    T *= (1.f - w);
  }
  const int idx = chunk * NPIX + p;
  g_part[0 * NCHUNK * NPIX + idx] = ar;
  g_part[1 * NCHUNK * NPIX + idx] = ag;
  g_part[2 * NCHUNK * NPIX + idx] = ab;
  g_part[3 * NCHUNK * NPIX + idx] = ad;
  g_part[4 * NCHUNK * NPIX + idx] = aa;
  g_part[5 * NCHUNK * NPIX + idx] = T;
}

// ---------------------------------------------------------------------------
// Kernel 3: fold the NCHUNK partials per pixel:  (C,T) ∘ (C',T') = (C+T·C', T·T')
// ---------------------------------------------------------------------------
__global__ __launch_bounds__(256) void combine_kernel(float* __restrict__ out) {
  const int p = blockIdx.x * 256 + threadIdx.x;
  float T = 1.f, r = 0.f, g = 0.f, b = 0.f, d = 0.f, a = 0.f;
#pragma unroll
  for (int ch = 0; ch < NCHUNK; ++ch) {
    const int idx = ch * NPIX + p;
    const float pr = g_part[0 * NCHUNK * NPIX + idx];
    const float pg = g_part[1 * NCHUNK * NPIX + idx];
    const float pb = g_part[2 * NCHUNK * NPIX + idx];
    const float pd = g_part[3 * NCHUNK * NPIX + idx];
    const float pa = g_part[4 * NCHUNK * NPIX + idx];
    const float pT = g_part[5 * NCHUNK * NPIX + idx];
    r += T * pr; g += T * pg; b += T * pb; d += T * pd; a += T * pa;
    T *= pT;
  }
  out[0 * NPIX + p] = r;
  out[1 * NPIX + p] = g;
  out[2 * NPIX + p] = b;
  out[3 * NPIX + p] = d;
  out[4 * NPIX + p] = a;
}

extern "C" void kernel_launch(void* const* d_in, const int* in_sizes, int n_in,
                              void* d_out, int out_size, void* d_ws, size_t ws_size,
                              hipStream_t stream) {
  const float* means = (const float*)d_in[0];
  const float* log_scales = (const float*)d_in[1];
  const float* quats = (const float*)d_in[2];
  const float* opacity_logits = (const float*)d_in[3];
  const float* colors = (const float*)d_in[4];
  const float* cam = (const float*)d_in[5];
  const float* look = (const float*)d_in[6];
  const float* up = (const float*)d_in[7];
  float* out = (float*)d_out;

  prep_sort_kernel<<<1, 1024, 0, stream>>>(means, log_scales, quats, opacity_logits,
                                           colors, cam, look, up);
  render_chunk_kernel<<<dim3(NPIX / 256, NCHUNK), 256, 0, stream>>>();
  combine_kernel<<<NPIX / 256, 256, 0, stream>>>(out);
}